// Round 5
// baseline (259.575 us; speedup 1.0000x reference)
//
#include <hip/hip_runtime.h>
#include <hip/hip_bf16.h>

#define LSEQ 512
#define DDIM 300

typedef __attribute__((ext_vector_type(8))) short short8;
typedef __attribute__((ext_vector_type(4))) float f32x4;

__device__ __forceinline__ void split4(f32x4 v, short8& hi, short8& lo, int base) {
  #pragma unroll
  for (int e = 0; e < 4; ++e) {
    const float f = v[e];
    const unsigned b = __float_as_uint(f);
    const float hf = __uint_as_float(b & 0xffff0000u);   // exact bf16-truncation
    hi[base + e] = (short)(b >> 16);
    lo[base + e] = (short)(__float_as_uint(f - hf) >> 16); // remainder, exact in f32
  }
}

__device__ __forceinline__ void gload_lds16(const float* g, float* l) {
  __builtin_amdgcn_global_load_lds((const __attribute__((address_space(1))) void*)g,
                                   (__attribute__((address_space(3))) void*)l,
                                   16, 0, 0);
}

template <int VM>
__device__ __forceinline__ void wait_vm() {
  asm volatile("s_waitcnt vmcnt(%0)" :: "n"(VM) : "memory");
  __builtin_amdgcn_sched_barrier(0);
}

// Stage one 16-edge tile (4 KB) into this wave's LDS buffer.
// LDS dest is linear (base + lane*16 per instr); the XOR swizzle is applied
// to the per-lane GLOBAL source so that the ds_read side can use the same
// involution (o ^= (edge&7)<<4) conflict-free.  [rule #21 / m173 pattern]
__device__ __forceinline__ void stage_tile(const float* __restrict__ gbase,
                                           float* lbuf, int lane) {
  const int ehi = lane >> 4;          // edge sub-index within instr
  const int olin = (lane & 15) << 4;  // linear byte offset within edge row
  #pragma unroll
  for (int i = 0; i < 4; ++i) {
    const int e = i * 4 + ehi;                    // edge 0..15
    const int o = olin ^ ((e & 7) << 4);          // swizzled source byte
    gload_lds16(gbase + e * 64 + (o >> 2), lbuf + i * 256);
  }
}

// Fused: ew = relu(emb @ W_map) @ w_ew  (split-bf16 MFMA, ~fp32 accuracy)
//        -> row-mean normalize -> adjacency mask -> softmax -> att row.
// One block per (b,i): 4 waves x 8 tiles x 16 edges.  emb is streamed via
// global_load_lds into a per-wave 3-buffer rotation with counted vmcnt(4),
// keeping 8 KB/wave of HBM reads permanently in flight (no barriers in loop).
__global__ __launch_bounds__(256, 3) void k_att(
    const float* __restrict__ emb, const int* __restrict__ adj,
    const float* __restrict__ Wmap, const float* __restrict__ wew,
    float* __restrict__ att) {
  __shared__ float stg[3][4][1024];   // 48 KB: 3 bufs x 4 waves x 4 KB
  __shared__ float ew_lds[LSEQ];
  __shared__ float redA[4], redB[4], redC[4];
  const int tid = threadIdx.x;
  const int lane = tid & 63, wid = tid >> 6;
  const int c = lane & 15, g = lane >> 4;
  const size_t rowbase = ((size_t)blockIdx.y * LSEQ + blockIdx.x) * LSEQ;
  const float* rowg = emb + (rowbase << 6);

  // ---- B fragments: W_map[k][h], k = 32*s + 8*g + e, col = 16*nt + c ----
  short8 bhi[4][2], blo[4][2];
  #pragma unroll
  for (int nt = 0; nt < 4; ++nt) {
    #pragma unroll
    for (int s = 0; s < 2; ++s) {
      #pragma unroll
      for (int e2 = 0; e2 < 2; ++e2) {
        f32x4 w;
        #pragma unroll
        for (int e = 0; e < 4; ++e)
          w[e] = Wmap[(32 * s + 8 * g + 4 * e2 + e) * 64 + 16 * nt + c];
        split4(w, bhi[nt][s], blo[nt][s], 4 * e2);
      }
    }
  }
  float wv[4];
  #pragma unroll
  for (int nt = 0; nt < 4; ++nt) wv[nt] = wew[16 * nt + c];

  float* const bufs[3] = {&stg[0][wid][0], &stg[1][wid][0], &stg[2][wid][0]};
  const int j0base = wid * 128;

  // swizzled ds_read word offsets (fixed per lane)
  const int sw = (c & 7) << 4;
  const int w0 = (((g << 5) + 0)   ^ sw) >> 2;
  const int w1 = (((g << 5) + 16)  ^ sw) >> 2;
  const int w2 = (((g << 5) + 128) ^ sw) >> 2;
  const int w3 = (((g << 5) + 144) ^ sw) >> 2;

  // prologue: 2 tiles in flight
  stage_tile(rowg + (size_t)(j0base + 0)  * 64, bufs[0], lane);
  stage_tile(rowg + (size_t)(j0base + 16) * 64, bufs[1], lane);

#define STEP(IT, DO_STAGE, VM)                                                  \
  {                                                                             \
    wait_vm<VM>();                                                              \
    if (DO_STAGE)                                                               \
      stage_tile(rowg + (size_t)(j0base + (IT + 2) * 16) * 64,                  \
                 bufs[(IT + 2) % 3], lane);                                     \
    const float* rbase = bufs[IT % 3] + (c << 6);                               \
    const f32x4 a0 = *(const f32x4*)(rbase + w0);                               \
    const f32x4 a1 = *(const f32x4*)(rbase + w1);                               \
    const f32x4 a2 = *(const f32x4*)(rbase + w2);                               \
    const f32x4 a3 = *(const f32x4*)(rbase + w3);                               \
    short8 ahi[2], alo[2];                                                      \
    split4(a0, ahi[0], alo[0], 0);                                              \
    split4(a1, ahi[0], alo[0], 4);                                              \
    split4(a2, ahi[1], alo[1], 0);                                              \
    split4(a3, ahi[1], alo[1], 4);                                              \
    f32x4 acc[4];                                                               \
    _Pragma("unroll")                                                           \
    for (int nt = 0; nt < 4; ++nt) acc[nt] = (f32x4){0.f, 0.f, 0.f, 0.f};       \
    _Pragma("unroll")                                                           \
    for (int s = 0; s < 2; ++s) {                                               \
      _Pragma("unroll")                                                         \
      for (int nt = 0; nt < 4; ++nt) {                                          \
        acc[nt] = __builtin_amdgcn_mfma_f32_16x16x32_bf16(ahi[s], bhi[nt][s], acc[nt], 0, 0, 0); \
        acc[nt] = __builtin_amdgcn_mfma_f32_16x16x32_bf16(ahi[s], blo[nt][s], acc[nt], 0, 0, 0); \
        acc[nt] = __builtin_amdgcn_mfma_f32_16x16x32_bf16(alo[s], bhi[nt][s], acc[nt], 0, 0, 0); \
      }                                                                         \
    }                                                                           \
    const int j0 = j0base + IT * 16;                                            \
    _Pragma("unroll")                                                           \
    for (int reg = 0; reg < 4; ++reg) {                                         \
      float p = 0.f;                                                            \
      _Pragma("unroll")                                                         \
      for (int nt = 0; nt < 4; ++nt) p = fmaf(fmaxf(acc[nt][reg], 0.f), wv[nt], p); \
      _Pragma("unroll")                                                         \
      for (int m = 1; m <= 8; m <<= 1) p += __shfl_xor(p, m, 64);               \
      if (c == 0) ew_lds[j0 + 4 * g + reg] = p;                                 \
    }                                                                           \
  }

  STEP(0, true, 4)
  STEP(1, true, 4)
  STEP(2, true, 4)
  STEP(3, true, 4)
  STEP(4, true, 4)
  STEP(5, true, 4)
  STEP(6, false, 4)
  STEP(7, false, 0)
#undef STEP

  __syncthreads();

  // ---- row-mean normalize + masked softmax ----
  const float ew0 = ew_lds[tid];
  const float ew1 = ew_lds[tid + 256];

  float ls = ew0 + ew1;
  #pragma unroll
  for (int m = 32; m >= 1; m >>= 1) ls += __shfl_xor(ls, m, 64);
  if (lane == 0) redA[wid] = ls;
  __syncthreads();
  const float rmean =
      fabsf((redA[0] + redA[1] + redA[2] + redA[3]) * (1.0f / 512.0f)) + 1e-10f;

  const int a0i = adj[rowbase + tid];
  const int a1i = adj[rowbase + tid + 256];
  const float sc0 = a0i ? (ew0 / rmean) : -9e15f;
  const float sc1 = a1i ? (ew1 / rmean) : -9e15f;

  float lm = fmaxf(sc0, sc1);
  #pragma unroll
  for (int m = 32; m >= 1; m >>= 1) lm = fmaxf(lm, __shfl_xor(lm, m, 64));
  if (lane == 0) redB[wid] = lm;
  __syncthreads();
  const float mx = fmaxf(fmaxf(redB[0], redB[1]), fmaxf(redB[2], redB[3]));

  const float e0 = expf(sc0 - mx);
  const float e1 = expf(sc1 - mx);
  float es = e0 + e1;
  #pragma unroll
  for (int m = 32; m >= 1; m >>= 1) es += __shfl_xor(es, m, 64);
  if (lane == 0) redC[wid] = es;
  __syncthreads();
  const float denom = redC[0] + redC[1] + redC[2] + redC[3];

  att[rowbase + tid] = e0 / denom;
  att[rowbase + tid + 256] = e1 / denom;
}

// h = x @ W_eto + b_eto.  16 rows per block; thread owns column d.
__global__ __launch_bounds__(320) void k_h(
    const float* __restrict__ x, const float* __restrict__ W,
    const float* __restrict__ bias, float* __restrict__ h) {
  const int d = threadIdx.x;
  const int r0 = blockIdx.x << 4;
  if (d >= DDIM) return;
  float acc[16];
  #pragma unroll
  for (int r = 0; r < 16; ++r) acc[r] = 0.f;
  #pragma unroll 4
  for (int k = 0; k < DDIM; ++k) {
    const float wv = W[k * DDIM + d];
    #pragma unroll
    for (int r = 0; r < 16; ++r)
      acc[r] = fmaf(x[(size_t)(r0 + r) * DDIM + k], wv, acc[r]);
  }
  const float bv = bias[d];
  #pragma unroll
  for (int r = 0; r < 16; ++r) h[(size_t)(r0 + r) * DDIM + d] = acc[r] + bv;
}

// h_edge = relu(att @ h).  16 i-rows per block; thread owns column d.
__global__ __launch_bounds__(320) void k_out(
    const float* __restrict__ att, const float* __restrict__ h,
    float* __restrict__ out) {
  const int d = threadIdx.x;
  const int b = blockIdx.y;
  const int i0 = blockIdx.x << 4;
  if (d >= DDIM) return;
  const float* attB = att + (size_t)b * LSEQ * LSEQ;
  const float* hB = h + (size_t)b * LSEQ * DDIM;
  float acc[16];
  #pragma unroll
  for (int r = 0; r < 16; ++r) acc[r] = 0.f;
  #pragma unroll 4
  for (int k = 0; k < LSEQ; ++k) {
    const float hv = hB[k * DDIM + d];
    #pragma unroll
    for (int r = 0; r < 16; ++r)
      acc[r] = fmaf(attB[(i0 + r) * LSEQ + k], hv, acc[r]);
  }
  #pragma unroll
  for (int r = 0; r < 16; ++r)
    out[((size_t)b * LSEQ + i0 + r) * DDIM + d] = fmaxf(acc[r], 0.f);
}

extern "C" void kernel_launch(void* const* d_in, const int* in_sizes, int n_in,
                              void* d_out, int out_size, void* d_ws, size_t ws_size,
                              hipStream_t stream) {
  const float* x    = (const float*)d_in[0];   // [8,512,300]
  const int*   adj  = (const int*)d_in[1];     // [8,512,512]
  const float* emb  = (const float*)d_in[2];   // [8,512,512,64]
  const float* Wmap = (const float*)d_in[3];   // [64,64]
  const float* wew  = (const float*)d_in[4];   // [64,1]
  const float* Weto = (const float*)d_in[5];   // [300,300]
  const float* beto = (const float*)d_in[6];   // [300]

  float* out    = (float*)d_out;
  float* h_edge = out;                               // [8,512,300]
  float* att    = out + (size_t)8 * LSEQ * DDIM;     // [8,512,512]
  float* h      = (float*)d_ws;                      // [8,512,300] scratch

  k_att<<<dim3(LSEQ, 8), 256, 0, stream>>>(emb, adj, Wmap, wew, att);
  k_h<<<dim3((8 * LSEQ) / 16), 320, 0, stream>>>(x, Weto, beto, h);
  k_out<<<dim3(LSEQ / 16, 8), 320, 0, stream>>>(att, h, h_edge);
}

// Round 6
// 233.763 us; speedup vs baseline: 1.1104x; 1.1104x over previous
//
#include <hip/hip_runtime.h>
#include <hip/hip_bf16.h>

#define LSEQ 512
#define DDIM 300

typedef __attribute__((ext_vector_type(8))) short short8;
typedef __attribute__((ext_vector_type(4))) float f32x4;

__device__ __forceinline__ void split4(f32x4 v, short8& hi, short8& lo, int base) {
  #pragma unroll
  for (int e = 0; e < 4; ++e) {
    const float f = v[e];
    const unsigned b = __float_as_uint(f);
    const float hf = __uint_as_float(b & 0xffff0000u);   // exact bf16-truncation
    hi[base + e] = (short)(b >> 16);
    lo[base + e] = (short)(__float_as_uint(f - hf) >> 16); // remainder, exact in f32
  }
}

// Streaming edge scores: ew[e] = relu(emb[e,:] @ W_map) @ w_ew, split-bf16 MFMA.
// Swapped operands: A = W_map fragments (m = h'), B = emb fragments (n = j).
// D[h' = 4g+reg][j = c]; epilogue = 16 in-lane fma + 2 shfl_xor.
// Waves independent: no LDS, no barriers. Each wave: 8 tiles x 16 edges = 128
// contiguous edges (32 KB), 1-deep register prefetch.
__global__ __launch_bounds__(256, 3) void k_ew(
    const float* __restrict__ emb, const float* __restrict__ Wmap,
    const float* __restrict__ wew, float* __restrict__ ew) {
  const int tid = threadIdx.x;
  const int lane = tid & 63, wid = tid >> 6;
  const int c = lane & 15, g = lane >> 4;

  // ---- A fragments: Wmap[k][h], k = 32*s + 8*g + e, h = 16*nt + c ----
  short8 whi[4][2], wlo[4][2];
  #pragma unroll
  for (int nt = 0; nt < 4; ++nt) {
    #pragma unroll
    for (int s = 0; s < 2; ++s) {
      #pragma unroll
      for (int e2 = 0; e2 < 2; ++e2) {
        f32x4 w;
        #pragma unroll
        for (int e = 0; e < 4; ++e)
          w[e] = Wmap[(32 * s + 8 * g + 4 * e2 + e) * 64 + 16 * nt + c];
        split4(w, whi[nt][s], wlo[nt][s], 4 * e2);
      }
    }
  }
  // per-lane w_ew values for h = 16*nt + 4*g + reg
  float wv2[4][4];
  #pragma unroll
  for (int nt = 0; nt < 4; ++nt)
    #pragma unroll
    for (int reg = 0; reg < 4; ++reg)
      wv2[nt][reg] = wew[16 * nt + 4 * g + reg];

  const size_t ebase = ((size_t)blockIdx.x * 4 + wid) * 128;  // first edge
  const float* base = emb + ((ebase + c) << 6) + 8 * g;

  f32x4 ca0 = *(const f32x4*)(base);
  f32x4 ca1 = *(const f32x4*)(base + 4);
  f32x4 ca2 = *(const f32x4*)(base + 32);
  f32x4 ca3 = *(const f32x4*)(base + 36);

  #pragma unroll 1
  for (int it = 0; it < 8; ++it) {
    const float* np = base + (size_t)((it + 1) & 7) * 1024;  // wraps on last
    const f32x4 na0 = *(const f32x4*)(np);
    const f32x4 na1 = *(const f32x4*)(np + 4);
    const f32x4 na2 = *(const f32x4*)(np + 32);
    const f32x4 na3 = *(const f32x4*)(np + 36);

    short8 ehi[2], elo[2];
    split4(ca0, ehi[0], elo[0], 0);
    split4(ca1, ehi[0], elo[0], 4);
    split4(ca2, ehi[1], elo[1], 0);
    split4(ca3, ehi[1], elo[1], 4);

    f32x4 acc[4];
    #pragma unroll
    for (int nt = 0; nt < 4; ++nt) acc[nt] = (f32x4){0.f, 0.f, 0.f, 0.f};
    #pragma unroll
    for (int s = 0; s < 2; ++s) {
      #pragma unroll
      for (int nt = 0; nt < 4; ++nt) {
        acc[nt] = __builtin_amdgcn_mfma_f32_16x16x32_bf16(whi[nt][s], ehi[s], acc[nt], 0, 0, 0);
        acc[nt] = __builtin_amdgcn_mfma_f32_16x16x32_bf16(whi[nt][s], elo[s], acc[nt], 0, 0, 0);
        acc[nt] = __builtin_amdgcn_mfma_f32_16x16x32_bf16(wlo[nt][s], ehi[s], acc[nt], 0, 0, 0);
      }
    }
    // p_lane = sum over this lane's 16 h-values; then reduce over the 4 g-groups
    float p = 0.f;
    #pragma unroll
    for (int nt = 0; nt < 4; ++nt)
      #pragma unroll
      for (int reg = 0; reg < 4; ++reg)
        p = fmaf(fmaxf(acc[nt][reg], 0.f), wv2[nt][reg], p);
    p += __shfl_xor(p, 16, 64);
    p += __shfl_xor(p, 32, 64);
    if (lane < 16) ew[ebase + it * 16 + c] = p;

    ca0 = na0; ca1 = na1; ca2 = na2; ca3 = na3;
  }
}

// Row-wise: mean -> abs -> normalize -> adjacency mask -> softmax.
// One 256-thread block per (b,i) row; identical numeric path to the
// previously-passing fused tail.
__global__ __launch_bounds__(256) void k_sm(
    const float* __restrict__ ew, const int* __restrict__ adj,
    float* __restrict__ att) {
  __shared__ float redA[4], redB[4], redC[4];
  const int tid = threadIdx.x;
  const int lane = tid & 63, wid = tid >> 6;
  const size_t rowbase = (size_t)blockIdx.x * LSEQ;

  const float ew0 = ew[rowbase + tid];
  const float ew1 = ew[rowbase + tid + 256];

  float ls = ew0 + ew1;
  #pragma unroll
  for (int m = 32; m >= 1; m >>= 1) ls += __shfl_xor(ls, m, 64);
  if (lane == 0) redA[wid] = ls;
  __syncthreads();
  const float rmean =
      fabsf((redA[0] + redA[1] + redA[2] + redA[3]) * (1.0f / 512.0f)) + 1e-10f;

  const int a0i = adj[rowbase + tid];
  const int a1i = adj[rowbase + tid + 256];
  const float sc0 = a0i ? (ew0 / rmean) : -9e15f;
  const float sc1 = a1i ? (ew1 / rmean) : -9e15f;

  float lm = fmaxf(sc0, sc1);
  #pragma unroll
  for (int m = 32; m >= 1; m >>= 1) lm = fmaxf(lm, __shfl_xor(lm, m, 64));
  if (lane == 0) redB[wid] = lm;
  __syncthreads();
  const float mx = fmaxf(fmaxf(redB[0], redB[1]), fmaxf(redB[2], redB[3]));

  const float e0 = expf(sc0 - mx);
  const float e1 = expf(sc1 - mx);
  float es = e0 + e1;
  #pragma unroll
  for (int m = 32; m >= 1; m >>= 1) es += __shfl_xor(es, m, 64);
  if (lane == 0) redC[wid] = es;
  __syncthreads();
  const float denom = redC[0] + redC[1] + redC[2] + redC[3];

  att[rowbase + tid] = e0 / denom;
  att[rowbase + tid + 256] = e1 / denom;
}

// h = x @ W_eto + b_eto.  16 rows per block; thread owns column d.
__global__ __launch_bounds__(320) void k_h(
    const float* __restrict__ x, const float* __restrict__ W,
    const float* __restrict__ bias, float* __restrict__ h) {
  const int d = threadIdx.x;
  const int r0 = blockIdx.x << 4;
  if (d >= DDIM) return;
  float acc[16];
  #pragma unroll
  for (int r = 0; r < 16; ++r) acc[r] = 0.f;
  #pragma unroll 4
  for (int k = 0; k < DDIM; ++k) {
    const float wv = W[k * DDIM + d];
    #pragma unroll
    for (int r = 0; r < 16; ++r)
      acc[r] = fmaf(x[(size_t)(r0 + r) * DDIM + k], wv, acc[r]);
  }
  const float bv = bias[d];
  #pragma unroll
  for (int r = 0; r < 16; ++r) h[(size_t)(r0 + r) * DDIM + d] = acc[r] + bv;
}

// h_edge = relu(att @ h).  16 i-rows per block; thread owns column d.
__global__ __launch_bounds__(320) void k_out(
    const float* __restrict__ att, const float* __restrict__ h,
    float* __restrict__ out) {
  const int d = threadIdx.x;
  const int b = blockIdx.y;
  const int i0 = blockIdx.x << 4;
  if (d >= DDIM) return;
  const float* attB = att + (size_t)b * LSEQ * LSEQ;
  const float* hB = h + (size_t)b * LSEQ * DDIM;
  float acc[16];
  #pragma unroll
  for (int r = 0; r < 16; ++r) acc[r] = 0.f;
  #pragma unroll 4
  for (int k = 0; k < LSEQ; ++k) {
    const float hv = hB[k * DDIM + d];
    #pragma unroll
    for (int r = 0; r < 16; ++r)
      acc[r] = fmaf(attB[(i0 + r) * LSEQ + k], hv, acc[r]);
  }
  #pragma unroll
  for (int r = 0; r < 16; ++r)
    out[((size_t)b * LSEQ + i0 + r) * DDIM + d] = fmaxf(acc[r], 0.f);
}

extern "C" void kernel_launch(void* const* d_in, const int* in_sizes, int n_in,
                              void* d_out, int out_size, void* d_ws, size_t ws_size,
                              hipStream_t stream) {
  const float* x    = (const float*)d_in[0];   // [8,512,300]
  const int*   adj  = (const int*)d_in[1];     // [8,512,512]
  const float* emb  = (const float*)d_in[2];   // [8,512,512,64]
  const float* Wmap = (const float*)d_in[3];   // [64,64]
  const float* wew  = (const float*)d_in[4];   // [64,1]
  const float* Weto = (const float*)d_in[5];   // [300,300]
  const float* beto = (const float*)d_in[6];   // [300]

  float* out    = (float*)d_out;
  float* h_edge = out;                               // [8,512,300]
  float* att    = out + (size_t)8 * LSEQ * DDIM;     // [8,512,512]
  float* ew     = (float*)d_ws;                      // [8,512,512] scratch (8 MB)
  float* h      = ew + (size_t)8 * LSEQ * LSEQ;      // [8,512,300] scratch (4.9 MB)

  // edge scores (streaming, independent waves)
  k_ew<<<dim3(4096), 256, 0, stream>>>(emb, Wmap, wew, ew);
  // row normalize + masked softmax
  k_sm<<<dim3(4096), 256, 0, stream>>>(ew, adj, att);
  // h = x @ W_eto + b
  k_h<<<dim3((8 * LSEQ) / 16), 320, 0, stream>>>(x, Weto, beto, h);
  // h_edge = relu(att @ h)
  k_out<<<dim3(LSEQ / 16, 8), 320, 0, stream>>>(att, h, h_edge);
}

// Round 7
// 223.723 us; speedup vs baseline: 1.1603x; 1.0449x over previous
//
#include <hip/hip_runtime.h>
#include <hip/hip_bf16.h>

#define LSEQ 512
#define DDIM 300

typedef __attribute__((ext_vector_type(8))) short short8;
typedef __attribute__((ext_vector_type(4))) float f32x4;

__device__ __forceinline__ void split4(f32x4 v, short8& hi, short8& lo, int base) {
  #pragma unroll
  for (int e = 0; e < 4; ++e) {
    const float f = v[e];
    const unsigned b = __float_as_uint(f);
    const float hf = __uint_as_float(b & 0xffff0000u);   // exact bf16-truncation
    hi[base + e] = (short)(b >> 16);
    lo[base + e] = (short)(__float_as_uint(f - hf) >> 16); // remainder, exact in f32
  }
}

// Streaming edge scores: ew[e] = relu(emb[e,:] @ W_map) @ w_ew, split-bf16 MFMA.
// A = W_map fragments, B = emb fragments; D[h'=4g+reg][j=c].
// GLOBAL loads are lane-DENSE (lane l <-> contiguous 16 B: the m13 6.3-TB/s
// pattern); a wave-private double-buffered LDS hop (XOR-swizzled b128
// write/read, no barriers) redistributes to the MFMA fragment layout.
// This is the single variable changed vs the R6 kernel (same numerics).
__global__ __launch_bounds__(256, 3) void k_ew(
    const float* __restrict__ emb, const float* __restrict__ Wmap,
    const float* __restrict__ wew, float* __restrict__ ew) {
  __shared__ float lds[2][4][1024];   // 32 KB: 2 bufs x 4 waves x 4 KB
  const int tid = threadIdx.x;
  const int lane = tid & 63, wid = tid >> 6;
  const int c = lane & 15, g = lane >> 4;

  // ---- A fragments: Wmap[k][h], k = 32*s + 8*g + e, h = 16*nt + c ----
  short8 whi[4][2], wlo[4][2];
  #pragma unroll
  for (int nt = 0; nt < 4; ++nt) {
    #pragma unroll
    for (int s = 0; s < 2; ++s) {
      #pragma unroll
      for (int e2 = 0; e2 < 2; ++e2) {
        f32x4 w;
        #pragma unroll
        for (int e = 0; e < 4; ++e)
          w[e] = Wmap[(32 * s + 8 * g + 4 * e2 + e) * 64 + 16 * nt + c];
        split4(w, whi[nt][s], wlo[nt][s], 4 * e2);
      }
    }
  }
  float wv2[4][4];
  #pragma unroll
  for (int nt = 0; nt < 4; ++nt)
    #pragma unroll
    for (int reg = 0; reg < 4; ++reg)
      wv2[nt][reg] = wew[16 * nt + 4 * g + reg];

  const size_t ebase = ((size_t)blockIdx.x * 4 + wid) * 128;  // first edge
  const float* gbase = emb + (ebase << 6);                    // 128 edges x 64 f

  float* const lb0 = &lds[0][wid][0];
  float* const lb1 = &lds[1][wid][0];

  // swizzled ds_write word offsets: linear byte B = i*1024 + lane*16,
  // row = B>>8, swizzle chunk-field by (row&7): B ^= ((row&7)<<4)
  int wwb[4];
  #pragma unroll
  for (int i = 0; i < 4; ++i)
    wwb[i] = ((i * 1024 + lane * 16) ^ ((((i & 1) * 4 + g) & 7) << 4)) >> 2;

  // swizzled ds_read word offsets: want row c, chunks {2g,2g+1,2g+8,2g+9}
  const int rw0 = (c * 256 + (((2 * g + 0) ^ (c & 7)) << 4)) >> 2;
  const int rw1 = (c * 256 + (((2 * g + 1) ^ (c & 7)) << 4)) >> 2;
  const int rw2 = (c * 256 + (((2 * g + 8) ^ (c & 7)) << 4)) >> 2;
  const int rw3 = (c * 256 + (((2 * g + 9) ^ (c & 7)) << 4)) >> 2;

  // prologue: dense-load tile 0 and write to buffer 0
  f32x4 q0 = *(const f32x4*)(gbase + 0 * 256 + lane * 4);
  f32x4 q1 = *(const f32x4*)(gbase + 1 * 256 + lane * 4);
  f32x4 q2 = *(const f32x4*)(gbase + 2 * 256 + lane * 4);
  f32x4 q3 = *(const f32x4*)(gbase + 3 * 256 + lane * 4);
  *(f32x4*)(lb0 + wwb[0]) = q0;
  *(f32x4*)(lb0 + wwb[1]) = q1;
  *(f32x4*)(lb0 + wwb[2]) = q2;
  *(f32x4*)(lb0 + wwb[3]) = q3;

  #pragma unroll 1
  for (int it = 0; it < 8; ++it) {
    if (it < 7) {  // dense prefetch of next tile into registers
      const float* nt_ = gbase + (size_t)(it + 1) * 1024;
      q0 = *(const f32x4*)(nt_ + 0 * 256 + lane * 4);
      q1 = *(const f32x4*)(nt_ + 1 * 256 + lane * 4);
      q2 = *(const f32x4*)(nt_ + 2 * 256 + lane * 4);
      q3 = *(const f32x4*)(nt_ + 3 * 256 + lane * 4);
    }
    float* const rb = (it & 1) ? lb1 : lb0;
    const f32x4 a0 = *(const f32x4*)(rb + rw0);
    const f32x4 a1 = *(const f32x4*)(rb + rw1);
    const f32x4 a2 = *(const f32x4*)(rb + rw2);
    const f32x4 a3 = *(const f32x4*)(rb + rw3);

    short8 ehi[2], elo[2];
    split4(a0, ehi[0], elo[0], 0);
    split4(a1, ehi[0], elo[0], 4);
    split4(a2, ehi[1], elo[1], 0);
    split4(a3, ehi[1], elo[1], 4);

    f32x4 acc[4];
    #pragma unroll
    for (int nt = 0; nt < 4; ++nt) acc[nt] = (f32x4){0.f, 0.f, 0.f, 0.f};
    #pragma unroll
    for (int s = 0; s < 2; ++s) {
      #pragma unroll
      for (int nt = 0; nt < 4; ++nt) {
        acc[nt] = __builtin_amdgcn_mfma_f32_16x16x32_bf16(whi[nt][s], ehi[s], acc[nt], 0, 0, 0);
        acc[nt] = __builtin_amdgcn_mfma_f32_16x16x32_bf16(whi[nt][s], elo[s], acc[nt], 0, 0, 0);
        acc[nt] = __builtin_amdgcn_mfma_f32_16x16x32_bf16(wlo[nt][s], ehi[s], acc[nt], 0, 0, 0);
      }
    }
    float p = 0.f;
    #pragma unroll
    for (int nt = 0; nt < 4; ++nt)
      #pragma unroll
      for (int reg = 0; reg < 4; ++reg)
        p = fmaf(fmaxf(acc[nt][reg], 0.f), wv2[nt][reg], p);
    p += __shfl_xor(p, 16, 64);
    p += __shfl_xor(p, 32, 64);
    if (lane < 16) ew[ebase + it * 16 + c] = p;

    if (it < 7) {  // stage prefetched tile into the other buffer
      float* const wb = (it & 1) ? lb0 : lb1;
      *(f32x4*)(wb + wwb[0]) = q0;
      *(f32x4*)(wb + wwb[1]) = q1;
      *(f32x4*)(wb + wwb[2]) = q2;
      *(f32x4*)(wb + wwb[3]) = q3;
    }
  }
}

// Row-wise: mean -> abs -> normalize -> adjacency mask -> softmax.
__global__ __launch_bounds__(256) void k_sm(
    const float* __restrict__ ew, const int* __restrict__ adj,
    float* __restrict__ att) {
  __shared__ float redA[4], redB[4], redC[4];
  const int tid = threadIdx.x;
  const int lane = tid & 63, wid = tid >> 6;
  const size_t rowbase = (size_t)blockIdx.x * LSEQ;

  const float ew0 = ew[rowbase + tid];
  const float ew1 = ew[rowbase + tid + 256];

  float ls = ew0 + ew1;
  #pragma unroll
  for (int m = 32; m >= 1; m >>= 1) ls += __shfl_xor(ls, m, 64);
  if (lane == 0) redA[wid] = ls;
  __syncthreads();
  const float rmean =
      fabsf((redA[0] + redA[1] + redA[2] + redA[3]) * (1.0f / 512.0f)) + 1e-10f;

  const int a0i = adj[rowbase + tid];
  const int a1i = adj[rowbase + tid + 256];
  const float sc0 = a0i ? (ew0 / rmean) : -9e15f;
  const float sc1 = a1i ? (ew1 / rmean) : -9e15f;

  float lm = fmaxf(sc0, sc1);
  #pragma unroll
  for (int m = 32; m >= 1; m >>= 1) lm = fmaxf(lm, __shfl_xor(lm, m, 64));
  if (lane == 0) redB[wid] = lm;
  __syncthreads();
  const float mx = fmaxf(fmaxf(redB[0], redB[1]), fmaxf(redB[2], redB[3]));

  const float e0 = expf(sc0 - mx);
  const float e1 = expf(sc1 - mx);
  float es = e0 + e1;
  #pragma unroll
  for (int m = 32; m >= 1; m >>= 1) es += __shfl_xor(es, m, 64);
  if (lane == 0) redC[wid] = es;
  __syncthreads();
  const float denom = redC[0] + redC[1] + redC[2] + redC[3];

  att[rowbase + tid] = e0 / denom;
  att[rowbase + tid + 256] = e1 / denom;
}

// h = x @ W_eto + b_eto.  16 rows per block; thread owns column d.
__global__ __launch_bounds__(320) void k_h(
    const float* __restrict__ x, const float* __restrict__ W,
    const float* __restrict__ bias, float* __restrict__ h) {
  const int d = threadIdx.x;
  const int r0 = blockIdx.x << 4;
  if (d >= DDIM) return;
  float acc[16];
  #pragma unroll
  for (int r = 0; r < 16; ++r) acc[r] = 0.f;
  #pragma unroll 4
  for (int k = 0; k < DDIM; ++k) {
    const float wv = W[k * DDIM + d];
    #pragma unroll
    for (int r = 0; r < 16; ++r)
      acc[r] = fmaf(x[(size_t)(r0 + r) * DDIM + k], wv, acc[r]);
  }
  const float bv = bias[d];
  #pragma unroll
  for (int r = 0; r < 16; ++r) h[(size_t)(r0 + r) * DDIM + d] = acc[r] + bv;
}

// h_edge = relu(att @ h).  16 i-rows per block; thread owns column d.
__global__ __launch_bounds__(320) void k_out(
    const float* __restrict__ att, const float* __restrict__ h,
    float* __restrict__ out) {
  const int d = threadIdx.x;
  const int b = blockIdx.y;
  const int i0 = blockIdx.x << 4;
  if (d >= DDIM) return;
  const float* attB = att + (size_t)b * LSEQ * LSEQ;
  const float* hB = h + (size_t)b * LSEQ * DDIM;
  float acc[16];
  #pragma unroll
  for (int r = 0; r < 16; ++r) acc[r] = 0.f;
  #pragma unroll 4
  for (int k = 0; k < LSEQ; ++k) {
    const float hv = hB[k * DDIM + d];
    #pragma unroll
    for (int r = 0; r < 16; ++r)
      acc[r] = fmaf(attB[(i0 + r) * LSEQ + k], hv, acc[r]);
  }
  #pragma unroll
  for (int r = 0; r < 16; ++r)
    out[((size_t)b * LSEQ + i0 + r) * DDIM + d] = fmaxf(acc[r], 0.f);
}

extern "C" void kernel_launch(void* const* d_in, const int* in_sizes, int n_in,
                              void* d_out, int out_size, void* d_ws, size_t ws_size,
                              hipStream_t stream) {
  const float* x    = (const float*)d_in[0];   // [8,512,300]
  const int*   adj  = (const int*)d_in[1];     // [8,512,512]
  const float* emb  = (const float*)d_in[2];   // [8,512,512,64]
  const float* Wmap = (const float*)d_in[3];   // [64,64]
  const float* wew  = (const float*)d_in[4];   // [64,1]
  const float* Weto = (const float*)d_in[5];   // [300,300]
  const float* beto = (const float*)d_in[6];   // [300]

  float* out    = (float*)d_out;
  float* h_edge = out;                               // [8,512,300]
  float* att    = out + (size_t)8 * LSEQ * DDIM;     // [8,512,512]
  float* ew     = (float*)d_ws;                      // [8,512,512] scratch (8 MB)
  float* h      = ew + (size_t)8 * LSEQ * LSEQ;      // [8,512,300] scratch (4.9 MB)

  k_ew<<<dim3(4096), 256, 0, stream>>>(emb, Wmap, wew, ew);
  k_sm<<<dim3(4096), 256, 0, stream>>>(ew, adj, att);
  k_h<<<dim3((8 * LSEQ) / 16), 320, 0, stream>>>(x, Weto, beto, h);
  k_out<<<dim3(LSEQ / 16, 8), 320, 0, stream>>>(att, h, h_edge);
}